// Round 4
// baseline (594.049 us; speedup 1.0000x reference)
//
#include <hip/hip_runtime.h>

#define F 256
#define NODE_BUDGET 200.0f
#define COS_EPS 1e-6f

#define BSHIFT 5                 // 32 nodes per bucket = 32KB x-window
#define PERM_CAP 128             // slots per bucket (mean fill ~80)
#define OVF_BLOCKS 64

// Per-root precompute: g[b][f] = x_root*w_ego_root*w_ego_u,
// nrinv[b] = 1/max(||x_root*w_ego_root||, eps), sv[b] = x_root . w_layer_v,
// bscale[b] = budgets[b]/200
__global__ __launch_bounds__(256) void root_kernel(
    const float* __restrict__ x,
    const float* __restrict__ w_ego_root,
    const float* __restrict__ w_ego_u,
    const float* __restrict__ w_layer_v,
    const float* __restrict__ budgets,
    const int* __restrict__ batch_nodes,
    float* __restrict__ g, float* __restrict__ nrinv,
    float* __restrict__ sv, float* __restrict__ bscale)
{
    __shared__ float red[2][4];
    int b = blockIdx.x;
    int f = threadIdx.x;  // F == 256 == blockDim.x
    int root = batch_nodes[b];
    float xf = x[(size_t)root * F + f];
    float hr = xf * w_ego_root[f];
    g[(size_t)b * F + f] = hr * w_ego_u[f];
    float a = hr * hr;
    float c = xf * w_layer_v[f];
    #pragma unroll
    for (int off = 32; off; off >>= 1) {
        a += __shfl_xor(a, off);
        c += __shfl_xor(c, off);
    }
    int lane = f & 63, wv = f >> 6;
    if (lane == 0) { red[0][wv] = a; red[1][wv] = c; }
    __syncthreads();
    if (f == 0) {
        float as = red[0][0] + red[0][1] + red[0][2] + red[0][3];
        float cs = red[1][0] + red[1][1] + red[1][2] + red[1][3];
        nrinv[b] = 1.0f / fmaxf(sqrtf(as), COS_EPS);
        sv[b] = cs;
        bscale[b] = budgets[b] * (1.0f / NODE_BUDGET);
    }
}

// Bucket-scatter: approximate counting sort of candidate ids by u>>BSHIFT.
// Ticket atomics into fixed-capacity buckets; overflow (prob ~1e-8/bucket at
// mean 80, cap 128) goes to a side list so every m is processed exactly once.
__global__ __launch_bounds__(256) void scatter_kernel(
    const int* __restrict__ u_ids, int* __restrict__ bcnt,
    int* __restrict__ perm, int* __restrict__ ovf, int* __restrict__ ovf_cnt,
    int M)
{
    int m = blockIdx.x * 256 + threadIdx.x;
    if (m >= M) return;
    int bk = u_ids[m] >> BSHIFT;
    int t = atomicAdd(&bcnt[bk], 1);
    if (t < PERM_CAP)
        perm[(bk << 7) + t] = m;          // PERM_CAP == 128 == 1<<7
    else
        ovf[atomicAdd(ovf_cnt, 1)] = m;
}

// agg[dst] += sv[src] over E edges (dst ~uniform over M=500k -> low contention)
__global__ __launch_bounds__(256) void edge_kernel(
    const int* __restrict__ edge_src, const int* __restrict__ edge_dst,
    const float* __restrict__ sv, float* __restrict__ agg, int E)
{
    int i = blockIdx.x * 256 + threadIdx.x;
    int stride = gridDim.x * 256;
    for (; i < E; i += stride)
        atomicAdd(&agg[edge_dst[i]], sv[edge_src[i]]);
}

// Flat R1-style candidate body: 16 lanes per candidate, fully independent.
__device__ __forceinline__ void process_cand(
    int m, int sl,
    const float* __restrict__ x,
    const int* __restrict__ u_ids, const int* __restrict__ batch_ptr,
    const float* __restrict__ g, const float* __restrict__ nrinv,
    const float* __restrict__ bscale, const float* __restrict__ agg,
    const float* __restrict__ w_ego_u, const float* __restrict__ w_layer_u,
    const float* __restrict__ n_imp, float* __restrict__ p_out)
{
    int u = u_ids[m];
    int b = batch_ptr[m];
    const float4* xr  = (const float4*)(x + (size_t)u * F);  // 32KB-window local
    const float4* gr  = (const float4*)(g + (size_t)b * F);  // L2-resident (1MB)
    const float4* weu = (const float4*)w_ego_u;              // L1-broadcast
    const float4* wlu = (const float4*)w_layer_u;            // L1-broadcast
    float acc = 0.0f, a2 = 0.0f, su = 0.0f;
    #pragma unroll
    for (int p = 0; p < 4; ++p) {
        float4 xv = xr[p * 16 + sl];
        float4 gv = gr[p * 16 + sl];
        float4 wu = weu[p * 16 + sl];
        float4 wl = wlu[p * 16 + sl];
        acc += xv.x * gv.x + xv.y * gv.y + xv.z * gv.z + xv.w * gv.w;
        float h0 = xv.x * wu.x, h1 = xv.y * wu.y, h2 = xv.z * wu.z, h3 = xv.w * wu.w;
        a2  += h0 * h0 + h1 * h1 + h2 * h2 + h3 * h3;
        su  += xv.x * wl.x + xv.y * wl.y + xv.z * wl.z + xv.w * wl.w;
    }
    #pragma unroll
    for (int off = 8; off; off >>= 1) {
        acc += __shfl_xor(acc, off);
        a2  += __shfl_xor(a2, off);
        su  += __shfl_xor(su, off);
    }
    if (sl == 0) {
        float nu = sqrtf(a2);
        float ego = acc * nrinv[b] / fmaxf(nu, COS_EPS);
        float layer = tanhf(agg[m] + su);
        p_out[m] = (0.5f * ego + 0.5f * layer) * n_imp[u] * bscale[b];
    }
}

// Walks perm slots in bucket order: consecutive waves touch the same 32KB
// x-window -> near-sequential HBM sweep, duplicate rows L1/L2-hit. Tail
// blocks drain the (normally empty) overflow list.
__global__ __launch_bounds__(256) void cand_perm_kernel(
    const float* __restrict__ x,
    const int* __restrict__ perm,
    const int* __restrict__ u_ids, const int* __restrict__ batch_ptr,
    const float* __restrict__ g, const float* __restrict__ nrinv,
    const float* __restrict__ bscale, const float* __restrict__ agg,
    const float* __restrict__ w_ego_u, const float* __restrict__ w_layer_u,
    const float* __restrict__ n_imp,
    const int* __restrict__ ovf, const int* __restrict__ ovf_cnt,
    float* __restrict__ p_out, int S, int mainBlocks)
{
    int tid = threadIdx.x;
    int lane = tid & 63;
    int sub = lane >> 4;          // which of 4 slots in this wave
    int sl = lane & 15;           // sub-lane within slot group
    if (blockIdx.x < (unsigned)mainBlocks) {
        int i = blockIdx.x * 16 + (tid >> 6) * 4 + sub;
        if (i >= S) return;
        int m = perm[i];
        if (m < 0) return;        // unfilled slot
        process_cand(m, sl, x, u_ids, batch_ptr, g, nrinv, bscale, agg,
                     w_ego_u, w_layer_u, n_imp, p_out);
    } else {
        int cnt = *ovf_cnt;
        int i = (blockIdx.x - mainBlocks) * 16 + (tid >> 6) * 4 + sub;
        int stride = OVF_BLOCKS * 16;
        for (; i < cnt; i += stride)
            process_cand(ovf[i], sl, x, u_ids, batch_ptr, g, nrinv, bscale, agg,
                         w_ego_u, w_layer_u, n_imp, p_out);
    }
}

// Fused segment-max + normalize: batch_ptr sorted -> contiguous segments.
// One block per b; binary-search bounds; max-reduce; normalize in place.
__global__ __launch_bounds__(256) void seg_norm_kernel(
    const int* __restrict__ batch_ptr, float* __restrict__ out, int M)
{
    int b = blockIdx.x;
    int lo = 0, hi = M;
    while (lo < hi) { int mid = (lo + hi) >> 1; if (batch_ptr[mid] < b) lo = mid + 1; else hi = mid; }
    int start = lo;
    hi = M;
    while (lo < hi) { int mid = (lo + hi) >> 1; if (batch_ptr[mid] <= b) lo = mid + 1; else hi = mid; }
    int end = lo;
    float mx = -INFINITY;
    for (int i = start + threadIdx.x; i < end; i += 256)
        mx = fmaxf(mx, out[i]);
    #pragma unroll
    for (int off = 32; off; off >>= 1)
        mx = fmaxf(mx, __shfl_xor(mx, off));
    __shared__ float red[4];
    __shared__ float s_pn;
    int lane = threadIdx.x & 63, wv = threadIdx.x >> 6;
    if (lane == 0) red[wv] = mx;
    __syncthreads();
    if (threadIdx.x == 0)
        s_pn = fmaxf(fmaxf(red[0], red[1]), fmaxf(red[2], red[3]));
    __syncthreads();
    float pn = s_pn;
    for (int i = start + threadIdx.x; i < end; i += 256) {
        float v = out[i] / pn + 1.0f;
        if (isnan(v)) v = 0.0f;
        else if (isinf(v)) v = 1.0f;
        out[i] = fminf(fmaxf(v, 1e-5f), 1.0f);
    }
}

extern "C" void kernel_launch(void* const* d_in, const int* in_sizes, int n_in,
                              void* d_out, int out_size, void* d_ws, size_t ws_size,
                              hipStream_t stream) {
    const float* x          = (const float*)d_in[0];
    const float* w_ego_root = (const float*)d_in[1];
    const float* w_ego_u    = (const float*)d_in[2];
    const float* w_layer_v  = (const float*)d_in[3];
    const float* w_layer_u  = (const float*)d_in[4];
    const float* n_imp      = (const float*)d_in[5];
    const float* budgets    = (const float*)d_in[6];
    const int* batch_nodes = (const int*)d_in[7];
    const int* u_ids       = (const int*)d_in[8];
    const int* batch_ptr   = (const int*)d_in[9];
    const int* edge_src    = (const int*)d_in[10];
    const int* edge_dst    = (const int*)d_in[11];
    float* out = (float*)d_out;

    int N = in_sizes[5];
    int B = in_sizes[7];
    int M = in_sizes[8];
    int E = in_sizes[10];

    int NB = (N + (1 << BSHIFT) - 1) >> BSHIFT;   // buckets
    int S = NB * PERM_CAP;                        // perm slots

    float* ws = (float*)d_ws;
    size_t off = 0;
    float* agg   = ws + off;                off += (size_t)((M + 3) & ~3);
    int* bcnt    = (int*)(ws + off);        off += (size_t)((NB + 3) & ~3);
    int* ovf_cnt = (int*)(ws + off);        off += 4;
    size_t zero_bytes = off * sizeof(float);      // agg + bcnt + ovf_cnt
    float* g      = ws + off;               off += (size_t)B * F;
    float* nrinv  = ws + off;               off += (size_t)((B + 3) & ~3);
    float* sv     = ws + off;               off += (size_t)((B + 3) & ~3);
    float* bscale = ws + off;               off += (size_t)((B + 3) & ~3);
    int* perm     = (int*)(ws + off);       off += (size_t)S;
    int* ovf      = (int*)(ws + off);       off += (size_t)((M + 3) & ~3);

    hipMemsetAsync(d_ws, 0, zero_bytes, stream);
    hipMemsetAsync(perm, 0xFF, (size_t)S * sizeof(int), stream);  // slots = -1

    scatter_kernel<<<(M + 255) / 256, 256, 0, stream>>>(u_ids, bcnt, perm, ovf,
                                                        ovf_cnt, M);
    root_kernel<<<B, 256, 0, stream>>>(x, w_ego_root, w_ego_u, w_layer_v,
                                       budgets, batch_nodes, g, nrinv, sv, bscale);
    edge_kernel<<<2048, 256, 0, stream>>>(edge_src, edge_dst, sv, agg, E);
    int mainBlocks = (S + 15) / 16;
    cand_perm_kernel<<<mainBlocks + OVF_BLOCKS, 256, 0, stream>>>(
        x, perm, u_ids, batch_ptr, g, nrinv, bscale, agg,
        w_ego_u, w_layer_u, n_imp, ovf, ovf_cnt, out, S, mainBlocks);
    seg_norm_kernel<<<B, 256, 0, stream>>>(batch_ptr, out, M);
}

// Round 5
// 544.171 us; speedup vs baseline: 1.0917x; 1.0917x over previous
//
#include <hip/hip_runtime.h>

#define F 256
#define NODE_BUDGET 200.0f
#define COS_EPS 1e-6f
#define TILE 2048               // scan tile: 256 threads x 8 elems

// Per-root precompute: g[b][f] = x_root*w_ego_root*w_ego_u,
// nrinv[b] = 1/max(||x_root*w_ego_root||, eps), sv[b] = x_root . w_layer_v,
// bscale[b] = budgets[b]/200
__global__ __launch_bounds__(256) void root_kernel(
    const float* __restrict__ x,
    const float* __restrict__ w_ego_root,
    const float* __restrict__ w_ego_u,
    const float* __restrict__ w_layer_v,
    const float* __restrict__ budgets,
    const int* __restrict__ batch_nodes,
    float* __restrict__ g, float* __restrict__ nrinv,
    float* __restrict__ sv, float* __restrict__ bscale)
{
    __shared__ float red[2][4];
    int b = blockIdx.x;
    int f = threadIdx.x;  // F == 256 == blockDim.x
    int root = batch_nodes[b];
    float xf = x[(size_t)root * F + f];
    float hr = xf * w_ego_root[f];
    g[(size_t)b * F + f] = hr * w_ego_u[f];
    float a = hr * hr;
    float c = xf * w_layer_v[f];
    #pragma unroll
    for (int off = 32; off; off >>= 1) {
        a += __shfl_xor(a, off);
        c += __shfl_xor(c, off);
    }
    int lane = f & 63, wv = f >> 6;
    if (lane == 0) { red[0][wv] = a; red[1][wv] = c; }
    __syncthreads();
    if (f == 0) {
        float as = red[0][0] + red[0][1] + red[0][2] + red[0][3];
        float cs = red[1][0] + red[1][1] + red[1][2] + red[1][3];
        nrinv[b] = 1.0f / fmaxf(sqrtf(as), COS_EPS);
        sv[b] = cs;
        bscale[b] = budgets[b] * (1.0f / NODE_BUDGET);
    }
}

// ---- exact counting sort of candidates by u ----
__global__ __launch_bounds__(256) void hist_kernel(
    const int* __restrict__ u_ids, int* __restrict__ cnt, int M)
{
    int m = blockIdx.x * 256 + threadIdx.x;
    if (m < M) atomicAdd(&cnt[u_ids[m]], 1);
}

// per-tile exclusive scan (TILE=2048 elems/block), tile sums to tsum
__global__ __launch_bounds__(256) void scan_tiles_kernel(
    const int* __restrict__ cnt, int* __restrict__ exc,
    int* __restrict__ tsum, int N)
{
    __shared__ int sh[256];
    int t = threadIdx.x;
    int base = blockIdx.x * TILE + t * 8;
    int v[8];
    int run = 0;
    #pragma unroll
    for (int k = 0; k < 8; ++k) {
        int c = (base + k < N) ? cnt[base + k] : 0;
        v[k] = run; run += c;
    }
    sh[t] = run;
    __syncthreads();
    // Hillis-Steele inclusive scan over 256 thread totals
    for (int off = 1; off < 256; off <<= 1) {
        int val = (t >= off) ? sh[t - off] : 0;
        __syncthreads();
        sh[t] += val;
        __syncthreads();
    }
    int texc = sh[t] - run;   // exclusive prefix of this thread
    #pragma unroll
    for (int k = 0; k < 8; ++k)
        if (base + k < N) exc[base + k] = v[k] + texc;
    if (t == 255) tsum[blockIdx.x] = sh[255];
}

// scan the (small) tile-sum array in place: inclusive->exclusive
__global__ void scan_sums_kernel(int* __restrict__ tsum, int NT)
{
    if (blockIdx.x == 0 && threadIdx.x == 0) {
        int run = 0;
        for (int i = 0; i < NT; ++i) { int c = tsum[i]; tsum[i] = run; run += c; }
    }
}

// cursor[u] = global exclusive prefix = exc[u] + tsum[tile(u)]
__global__ __launch_bounds__(256) void add_offsets_kernel(
    const int* __restrict__ exc, const int* __restrict__ tsum,
    int* __restrict__ cursor, int N)
{
    int base = blockIdx.x * TILE + threadIdx.x * 8;
    int add = tsum[blockIdx.x];
    #pragma unroll
    for (int k = 0; k < 8; ++k)
        if (base + k < N) cursor[base + k] = exc[base + k] + add;
}

// sorted_m[pos] = m, pos = cursor[u]++  (order within u irrelevant)
__global__ __launch_bounds__(256) void scatter_sorted_kernel(
    const int* __restrict__ u_ids, int* __restrict__ cursor,
    int* __restrict__ sorted_m, int M)
{
    int m = blockIdx.x * 256 + threadIdx.x;
    if (m >= M) return;
    int pos = atomicAdd(&cursor[u_ids[m]], 1);
    sorted_m[pos] = m;
}

// agg[dst] += sv[src] over E edges (dst ~uniform over M=500k -> low contention)
__global__ __launch_bounds__(256) void edge_kernel(
    const int* __restrict__ edge_src, const int* __restrict__ edge_dst,
    const float* __restrict__ sv, float* __restrict__ agg, int E)
{
    int i = blockIdx.x * 256 + threadIdx.x;
    int stride = gridDim.x * 256;
    for (; i < E; i += stride)
        atomicAdd(&agg[edge_dst[i]], sv[edge_src[i]]);
}

// R1 flat body (16 lanes/candidate), but processed in u-sorted order with a
// bijective XCD chunk swizzle: XCD k sweeps a CONTIGUOUS slice of the sorted
// order -> its x reads are a sequential ~25MB sweep, duplicate rows adjacent
// (same XCD's L2 hits). g gathers random but g = 1MB, L2-resident everywhere.
__global__ __launch_bounds__(256) void cand_sorted_kernel(
    const float* __restrict__ x,
    const int* __restrict__ sorted_m,
    const int* __restrict__ u_ids, const int* __restrict__ batch_ptr,
    const float* __restrict__ g, const float* __restrict__ nrinv,
    const float* __restrict__ bscale, const float* __restrict__ agg,
    const float* __restrict__ w_ego_u, const float* __restrict__ w_layer_u,
    const float* __restrict__ n_imp,
    float* __restrict__ p_out, int M)
{
    // bijective XCD swizzle (8 XCDs): orig -> contiguous per-XCD chunk
    int G = gridDim.x;
    int bid = blockIdx.x;
    int q = G >> 3, r = G & 7, xc = bid & 7, j = bid >> 3;
    int wg = (xc < r ? xc * (q + 1) : r * (q + 1) + (xc - r) * q) + j;

    int tid = threadIdx.x;
    int lane = tid & 63;
    int sub = lane >> 4;          // which of 4 candidates in this wave
    int sl = lane & 15;           // sub-lane within candidate group
    int i = wg * 16 + (tid >> 6) * 4 + sub;
    if (i >= M) return;
    int m = sorted_m[i];
    int u = u_ids[m];
    int b = batch_ptr[m];
    const float4* xr  = (const float4*)(x + (size_t)u * F);  // sequential sweep
    const float4* gr  = (const float4*)(g + (size_t)b * F);  // L2-resident (1MB)
    const float4* weu = (const float4*)w_ego_u;              // L1-broadcast
    const float4* wlu = (const float4*)w_layer_u;            // L1-broadcast
    float acc = 0.0f, a2 = 0.0f, su = 0.0f;
    #pragma unroll
    for (int p = 0; p < 4; ++p) {
        float4 xv = xr[p * 16 + sl];
        float4 gv = gr[p * 16 + sl];
        float4 wu = weu[p * 16 + sl];
        float4 wl = wlu[p * 16 + sl];
        acc += xv.x * gv.x + xv.y * gv.y + xv.z * gv.z + xv.w * gv.w;
        float h0 = xv.x * wu.x, h1 = xv.y * wu.y, h2 = xv.z * wu.z, h3 = xv.w * wu.w;
        a2  += h0 * h0 + h1 * h1 + h2 * h2 + h3 * h3;
        su  += xv.x * wl.x + xv.y * wl.y + xv.z * wl.z + xv.w * wl.w;
    }
    #pragma unroll
    for (int off = 8; off; off >>= 1) {
        acc += __shfl_xor(acc, off);
        a2  += __shfl_xor(a2, off);
        su  += __shfl_xor(su, off);
    }
    if (sl == 0) {
        float nu = sqrtf(a2);
        float ego = acc * nrinv[b] / fmaxf(nu, COS_EPS);
        float layer = tanhf(agg[m] + su);
        p_out[m] = (0.5f * ego + 0.5f * layer) * n_imp[u] * bscale[b];
    }
}

// Fused segment-max + normalize: batch_ptr sorted -> contiguous segments.
__global__ __launch_bounds__(256) void seg_norm_kernel(
    const int* __restrict__ batch_ptr, float* __restrict__ out, int M)
{
    int b = blockIdx.x;
    int lo = 0, hi = M;
    while (lo < hi) { int mid = (lo + hi) >> 1; if (batch_ptr[mid] < b) lo = mid + 1; else hi = mid; }
    int start = lo;
    hi = M;
    while (lo < hi) { int mid = (lo + hi) >> 1; if (batch_ptr[mid] <= b) lo = mid + 1; else hi = mid; }
    int end = lo;
    float mx = -INFINITY;
    for (int i = start + threadIdx.x; i < end; i += 256)
        mx = fmaxf(mx, out[i]);
    #pragma unroll
    for (int off = 32; off; off >>= 1)
        mx = fmaxf(mx, __shfl_xor(mx, off));
    __shared__ float red[4];
    __shared__ float s_pn;
    int lane = threadIdx.x & 63, wv = threadIdx.x >> 6;
    if (lane == 0) red[wv] = mx;
    __syncthreads();
    if (threadIdx.x == 0)
        s_pn = fmaxf(fmaxf(red[0], red[1]), fmaxf(red[2], red[3]));
    __syncthreads();
    float pn = s_pn;
    for (int i = start + threadIdx.x; i < end; i += 256) {
        float v = out[i] / pn + 1.0f;
        if (isnan(v)) v = 0.0f;
        else if (isinf(v)) v = 1.0f;
        out[i] = fminf(fmaxf(v, 1e-5f), 1.0f);
    }
}

extern "C" void kernel_launch(void* const* d_in, const int* in_sizes, int n_in,
                              void* d_out, int out_size, void* d_ws, size_t ws_size,
                              hipStream_t stream) {
    const float* x          = (const float*)d_in[0];
    const float* w_ego_root = (const float*)d_in[1];
    const float* w_ego_u    = (const float*)d_in[2];
    const float* w_layer_v  = (const float*)d_in[3];
    const float* w_layer_u  = (const float*)d_in[4];
    const float* n_imp      = (const float*)d_in[5];
    const float* budgets    = (const float*)d_in[6];
    const int* batch_nodes = (const int*)d_in[7];
    const int* u_ids       = (const int*)d_in[8];
    const int* batch_ptr   = (const int*)d_in[9];
    const int* edge_src    = (const int*)d_in[10];
    const int* edge_dst    = (const int*)d_in[11];
    float* out = (float*)d_out;

    int N = in_sizes[5];
    int B = in_sizes[7];
    int M = in_sizes[8];
    int E = in_sizes[10];

    int NT = (N + TILE - 1) / TILE;   // scan tiles

    float* ws = (float*)d_ws;
    size_t off = 0;
    float* agg  = ws + off;                 off += (size_t)((M + 3) & ~3);
    int* cnt    = (int*)(ws + off);         off += (size_t)((N + 3) & ~3);
    size_t zero_bytes = off * sizeof(float);      // agg + cnt
    float* g      = ws + off;               off += (size_t)B * F;
    float* nrinv  = ws + off;               off += (size_t)((B + 3) & ~3);
    float* sv     = ws + off;               off += (size_t)((B + 3) & ~3);
    float* bscale = ws + off;               off += (size_t)((B + 3) & ~3);
    int* exc      = (int*)(ws + off);       off += (size_t)((N + 3) & ~3);
    int* tsum     = (int*)(ws + off);       off += (size_t)((NT + 3) & ~3);
    int* cursor   = (int*)(ws + off);       off += (size_t)((N + 3) & ~3);
    int* sorted_m = (int*)(ws + off);       off += (size_t)((M + 3) & ~3);

    hipMemsetAsync(d_ws, 0, zero_bytes, stream);

    hist_kernel<<<(M + 255) / 256, 256, 0, stream>>>(u_ids, cnt, M);
    scan_tiles_kernel<<<NT, 256, 0, stream>>>(cnt, exc, tsum, N);
    scan_sums_kernel<<<1, 64, 0, stream>>>(tsum, NT);
    add_offsets_kernel<<<NT, 256, 0, stream>>>(exc, tsum, cursor, N);
    scatter_sorted_kernel<<<(M + 255) / 256, 256, 0, stream>>>(u_ids, cursor,
                                                               sorted_m, M);
    root_kernel<<<B, 256, 0, stream>>>(x, w_ego_root, w_ego_u, w_layer_v,
                                       budgets, batch_nodes, g, nrinv, sv, bscale);
    edge_kernel<<<2048, 256, 0, stream>>>(edge_src, edge_dst, sv, agg, E);
    cand_sorted_kernel<<<(M + 15) / 16, 256, 0, stream>>>(
        x, sorted_m, u_ids, batch_ptr, g, nrinv, bscale, agg,
        w_ego_u, w_layer_u, n_imp, out, M);
    seg_norm_kernel<<<B, 256, 0, stream>>>(batch_ptr, out, M);
}